// Round 4
// baseline (1319.847 us; speedup 1.0000x reference)
//
#include <hip/hip_runtime.h>

#define BB 32
#define NN 576
#define DD 1024
#define KK 128
#define HS_N 577

// ---------------- norm kernel: inv[b,n] = 1/||feats[b,n,:]|| ----------------
__global__ __launch_bounds__(256) void norm_kernel(const float* __restrict__ hs,
                                                   float* __restrict__ inv) {
    int row = blockIdx.x;              // b*NN + n
    int b = row / NN, n = row % NN;
    const float4* p = (const float4*)(hs + ((size_t)b * HS_N + n + 1) * DD);
    int t = threadIdx.x;
    float4 v = p[t];
    double s = (double)v.x * v.x + (double)v.y * v.y + (double)v.z * v.z + (double)v.w * v.w;
    for (int off = 32; off; off >>= 1) s += __shfl_xor(s, off);
    __shared__ double wsum[4];
    int lane = t & 63, w = t >> 6;
    if (lane == 0) wsum[w] = s;
    __syncthreads();
    if (t == 0) {
        double tot = wsum[0] + wsum[1] + wsum[2] + wsum[3];
        inv[row] = 1.0f / (float)sqrt(tot);
    }
}

// ---------------- sim GEMM (symmetric): only 45 upper-tri 64x64 tile pairs --
#define KC 16
#define LDT 68   // padded LDS stride
#define TLD 68   // transpose-bounce stride
__global__ __launch_bounds__(256) void sim_kernel(const float* __restrict__ hs,
                                                  const float* __restrict__ inv,
                                                  float* __restrict__ sim) {
    int b = blockIdx.z;
    int l = blockIdx.x;                // 0..44 -> (ti,tj), ti<=tj
    int ti = 0;
    while (l >= 9 - ti) { l -= 9 - ti; ti++; }
    int tj = ti + l;
    int m0 = ti * 64, n0 = tj * 64;
    const float* feats = hs + ((size_t)b * HS_N + 1) * DD;
    __shared__ float As[KC * LDT];
    __shared__ float Bs[KC * LDT];
    __shared__ float tile[64 * TLD];
    int t = threadIdx.x;
    int lrow = t >> 2, lc4 = (t & 3) << 2;     // 64 rows x 4 float4-cols
    float invA = inv[b * NN + m0 + lrow];
    float invB = inv[b * NN + n0 + lrow];
    const float* gA = feats + (size_t)(m0 + lrow) * DD + lc4;
    const float* gB = feats + (size_t)(n0 + lrow) * DD + lc4;
    int tx = t & 15, ty = t >> 4;
    float acc[4][4] = {};
    for (int k0 = 0; k0 < DD; k0 += KC) {
        float4 a = *(const float4*)(gA + k0);
        float4 bv = *(const float4*)(gB + k0);
        __syncthreads();
        // store transposed [k][m], scaled at load (matches reference normalize-then-dot)
        As[(lc4 + 0) * LDT + lrow] = a.x * invA;
        As[(lc4 + 1) * LDT + lrow] = a.y * invA;
        As[(lc4 + 2) * LDT + lrow] = a.z * invA;
        As[(lc4 + 3) * LDT + lrow] = a.w * invA;
        Bs[(lc4 + 0) * LDT + lrow] = bv.x * invB;
        Bs[(lc4 + 1) * LDT + lrow] = bv.y * invB;
        Bs[(lc4 + 2) * LDT + lrow] = bv.z * invB;
        Bs[(lc4 + 3) * LDT + lrow] = bv.w * invB;
        __syncthreads();
#pragma unroll
        for (int kk = 0; kk < KC; kk++) {
            float4 av = *(const float4*)&As[kk * LDT + (tx << 2)];
            float4 bw = *(const float4*)&Bs[kk * LDT + (ty << 2)];
            float aa[4] = {av.x, av.y, av.z, av.w};
            float bb[4] = {bw.x, bw.y, bw.z, bw.w};
#pragma unroll
            for (int i = 0; i < 4; i++)
#pragma unroll
                for (int j = 0; j < 4; j++) acc[i][j] += aa[i] * bb[j];
        }
    }
    // normal-orientation tile write (coalesced float4)
#pragma unroll
    for (int i = 0; i < 4; i++) {
        size_t m = m0 + (tx << 2) + i;
        float4 o = {acc[i][0], acc[i][1], acc[i][2], acc[i][3]};
        *(float4*)(sim + ((size_t)b * NN + m) * NN + n0 + (ty << 2)) = o;
    }
    if (ti != tj) {
        // mirror tile via LDS bounce; same float values -> bitwise symmetric
        __syncthreads();
#pragma unroll
        for (int i = 0; i < 4; i++) {
            float4 o = {acc[i][0], acc[i][1], acc[i][2], acc[i][3]};
            *(float4*)&tile[((tx << 2) + i) * TLD + (ty << 2)] = o;
        }
        __syncthreads();
#pragma unroll
        for (int r = 0; r < 4; r++) {
            int a = (tx << 2) + r;                 // local n index (output row)
            float4 o;
            o.x = tile[((ty << 2) + 0) * TLD + a];
            o.y = tile[((ty << 2) + 1) * TLD + a];
            o.z = tile[((ty << 2) + 2) * TLD + a];
            o.w = tile[((ty << 2) + 3) * TLD + a];
            *(float4*)(sim + ((size_t)b * NN + n0 + a) * NN + m0 + (ty << 2)) = o;
        }
    }
}

// ------- selection: barrier-free, 3 waves, LDS tag handshakes ---------------
// Thread owns 3 candidates I_u = 64*(3u+w)+lane. gain[m] (fp64) incrementally
// maintained; per step: poll done-tags -> delta-update -> wave argmax ->
// post (rv,ri,rtag) -> poll rtags -> scan -> row-mstar load -> own-chunk cmax
// update + segment compaction -> post done-tag. Single-buffer safety: a wave
// can only write step-k state after ALL waves posted step-k rtags, which
// requires their phase-1 reads of step-(k-1) state to be complete.
// Deterministic update order (ascending n) -> exact-reproducible selections.
__global__ __launch_bounds__(192) void select_kernel(const float* __restrict__ sim,
                                                     const float* __restrict__ cls,
                                                     float* __restrict__ out_idx,
                                                     int* __restrict__ gsorted) {
    int b = blockIdx.x;
    const float* S = sim + (size_t)b * NN * NN;
    int t = threadIdx.x, lane = t & 63, w = t >> 6;   // w in 0..2
    __shared__ float cmax[NN];
    __shared__ float oldv[NN];
    __shared__ int   chlist[NN];       // 9 segments of 64 (chunk c = 3u+w)
    __shared__ int   wcnt[9];
    __shared__ double rv[3];
    __shared__ int    ri[3];
    __shared__ int    rtag[3];
    __shared__ int    done[3];
    volatile int* vrtag = rtag;
    volatile int* vdone = done;

    int iu[3];
    double g[3];
    bool sel[3] = {false, false, false};
    float clsv[3];
#pragma unroll
    for (int u = 0; u < 3; u++) {
        iu[u] = 64 * (3 * u + w) + lane;
        clsv[u] = cls[b * NN + iu[u]];
        cmax[iu[u]] = 0.f;
        g[u] = 0.0;
    }
    if (lane == 0) { rtag[w] = -1; done[w] = -1; }

    // initial gains: ascending n, ILP 16x3 coalesced column reads
    for (int n0 = 0; n0 < NN; n0 += 16) {
        float s_[16][3];
#pragma unroll
        for (int q = 0; q < 16; q++) {
            const float* rp = S + (size_t)(n0 + q) * NN;
#pragma unroll
            for (int u = 0; u < 3; u++) s_[q][u] = rp[iu[u]];
        }
#pragma unroll
        for (int q = 0; q < 16; q++)
#pragma unroll
            for (int u = 0; u < 3; u++) g[u] += (double)fmaxf(s_[q][u], 0.f);
    }
    __syncthreads();   // covers cmax + tag init

    for (int k = 0; k < KK; k++) {
        // ---- phase 1: delta-update g over step-(k-1) changed columns ----
        if (k > 0) {
            int km1 = k - 1;
            while (vdone[0] < km1 || vdone[1] < km1 || vdone[2] < km1) {}
            __threadfence_block();
            int pf[10]; pf[0] = 0;
#pragma unroll
            for (int c = 0; c < 9; c++) pf[c + 1] = pf[c] + wcnt[c];
            int tot = pf[9];
            for (int f0 = 0; f0 < tot; f0 += 16) {
                int nn_[16]; float s_[16][3];
#pragma unroll
                for (int q = 0; q < 16; q++) {
                    int f = f0 + q; if (f > tot - 1) f = tot - 1;
                    int c = 0;
#pragma unroll
                    for (int e = 1; e < 9; e++) c += (f >= pf[e]);
                    nn_[q] = chlist[64 * c + (f - pf[c])];
                }
#pragma unroll
                for (int q = 0; q < 16; q++) {
                    const float* rp = S + (size_t)nn_[q] * NN;
#pragma unroll
                    for (int u = 0; u < 3; u++) s_[q][u] = rp[iu[u]];
                }
#pragma unroll
                for (int q = 0; q < 16; q++) {
                    bool val = (f0 + q) < tot;
                    float o = oldv[nn_[q]], nw = cmax[nn_[q]];
#pragma unroll
                    for (int u = 0; u < 3; u++) {
                        double d = (double)fmaxf(s_[q][u] - nw, 0.f)
                                 - (double)fmaxf(s_[q][u] - o, 0.f);
                        g[u] += val ? d : 0.0;
                    }
                }
            }
        }
        // ---- wave argmax (smallest-index tie-break, iu ascending in u) ----
        double v = sel[0] ? -1.0 : g[0] * (double)clsv[0];
        int idx = iu[0];
#pragma unroll
        for (int u = 1; u < 3; u++) {
            double vu = sel[u] ? -1.0 : g[u] * (double)clsv[u];
            if (vu > v) { v = vu; idx = iu[u]; }
        }
        for (int off = 32; off; off >>= 1) {
            double ov = __shfl_xor(v, off);
            int oi = __shfl_xor(idx, off);
            if (ov > v || (ov == v && oi < idx)) { v = ov; idx = oi; }
        }
        if (lane == 0) { rv[w] = v; ri[w] = idx; __threadfence_block(); vrtag[w] = k; }
        // ---- cross-wave scan via tag poll ----
        while (vrtag[0] < k || vrtag[1] < k || vrtag[2] < k) {}
        __threadfence_block();
        double bv = rv[0]; int mstar = ri[0];
#pragma unroll
        for (int q = 1; q < 3; q++) {
            double qv = rv[q]; int qi = ri[q];
            if (qv > bv || (qv == bv && qi < mstar)) { bv = qv; mstar = qi; }
        }
        // ---- update own chunks, segment compaction ----
        const float* rowm = S + (size_t)mstar * NN;
        float sv_[3];
#pragma unroll
        for (int u = 0; u < 3; u++) sv_[u] = rowm[iu[u]];
#pragma unroll
        for (int u = 0; u < 3; u++) {
            float old = cmax[iu[u]];
            float nw = fmaxf(old, sv_[u]);
            bool ch = nw > old;
            unsigned long long mask = __ballot(ch);
            int rank = __popcll(mask & ((1ull << lane) - 1));
            oldv[iu[u]] = old;
            cmax[iu[u]] = nw;
            int c = 3 * u + w;
            if (lane == 0) wcnt[c] = __popcll(mask);
            if (ch) chlist[64 * c + rank] = iu[u];
            if (iu[u] == mstar) { sel[u] = true; out_idx[b * KK + k] = (float)(mstar + 1); }
        }
        __threadfence_block();
        if (lane == 0) vdone[w] = k;
    }

    // ---- epilogue: sorted gather list (ascending index compaction) ----
    __syncthreads();
#pragma unroll
    for (int u = 0; u < 3; u++) {
        unsigned long long mask = __ballot(sel[u]);
        if (lane == 0) wcnt[3 * u + w] = __popcll(mask);
    }
    __syncthreads();
#pragma unroll
    for (int u = 0; u < 3; u++) {
        unsigned long long mask = __ballot(sel[u]);
        int rank = __popcll(mask & ((1ull << lane) - 1));
        int c = 3 * u + w;
        int pre = 0;
        for (int q = 0; q < 9; q++) if (q < c) pre += wcnt[q];
        if (sel[u]) gsorted[b * KK + pre + rank] = iu[u] + 1;
    }
}

// ---------------- gather: dominant_tokens[b,j,:] = hs[b, gsorted, :] --------
__global__ __launch_bounds__(256) void gather_kernel(const float* __restrict__ hs,
                                                     const int* __restrict__ gsorted,
                                                     float* __restrict__ out) {
    int blk = blockIdx.x;
    int b = blk >> 7, j = blk & 127;
    int row = gsorted[b * KK + j];
    const float4* src = (const float4*)(hs + ((size_t)b * HS_N + row) * DD);
    float4* dst = (float4*)(out + ((size_t)b * KK + j) * DD);
    dst[threadIdx.x] = src[threadIdx.x];
}

extern "C" void kernel_launch(void* const* d_in, const int* in_sizes, int n_in,
                              void* d_out, int out_size, void* d_ws, size_t ws_size,
                              hipStream_t stream) {
    const float* hs = (const float*)d_in[0];
    const float* cls = (const float*)d_in[1];
    // workspace layout: sim (42.5MB) | inv (73KB) | gsorted (16KB)
    float* sim = (float*)d_ws;
    float* inv = sim + (size_t)BB * NN * NN;
    int* gsorted = (int*)(inv + BB * NN);
    float* out_tokens = (float*)d_out;                       // [B,K,D] fp32
    float* out_idx = out_tokens + (size_t)BB * KK * DD;      // [B,K] indices as fp32

    norm_kernel<<<BB * NN, 256, 0, stream>>>(hs, inv);
    sim_kernel<<<dim3(45, 1, BB), 256, 0, stream>>>(hs, inv, sim);
    select_kernel<<<BB, 192, 0, stream>>>(sim, cls, out_idx, gsorted);
    gather_kernel<<<BB * KK, 256, 0, stream>>>(hs, gsorted, out_tokens);
}

// Round 5
// 1021.076 us; speedup vs baseline: 1.2926x; 1.2926x over previous
//
#include <hip/hip_runtime.h>

#define BB 32
#define NN 576
#define DD 1024
#define KK 128
#define HS_N 577

// ---------------- norm kernel: inv[b,n] = 1/||feats[b,n,:]|| ----------------
__global__ __launch_bounds__(256) void norm_kernel(const float* __restrict__ hs,
                                                   float* __restrict__ inv) {
    int row = blockIdx.x;              // b*NN + n
    int b = row / NN, n = row % NN;
    const float4* p = (const float4*)(hs + ((size_t)b * HS_N + n + 1) * DD);
    int t = threadIdx.x;
    float4 v = p[t];
    double s = (double)v.x * v.x + (double)v.y * v.y + (double)v.z * v.z + (double)v.w * v.w;
    for (int off = 32; off; off >>= 1) s += __shfl_xor(s, off);
    __shared__ double wsum[4];
    int lane = t & 63, w = t >> 6;
    if (lane == 0) wsum[w] = s;
    __syncthreads();
    if (t == 0) {
        double tot = wsum[0] + wsum[1] + wsum[2] + wsum[3];
        inv[row] = 1.0f / (float)sqrt(tot);
    }
}

// ---------------- sim GEMM (symmetric): only 45 upper-tri 64x64 tile pairs --
#define KC 16
#define LDT 68   // padded LDS stride
#define TLD 68   // transpose-bounce stride
__global__ __launch_bounds__(256) void sim_kernel(const float* __restrict__ hs,
                                                  const float* __restrict__ inv,
                                                  float* __restrict__ sim) {
    int b = blockIdx.z;
    int l = blockIdx.x;                // 0..44 -> (ti,tj), ti<=tj
    int ti = 0;
    while (l >= 9 - ti) { l -= 9 - ti; ti++; }
    int tj = ti + l;
    int m0 = ti * 64, n0 = tj * 64;
    const float* feats = hs + ((size_t)b * HS_N + 1) * DD;
    __shared__ float As[KC * LDT];
    __shared__ float Bs[KC * LDT];
    __shared__ float tile[64 * TLD];
    int t = threadIdx.x;
    int lrow = t >> 2, lc4 = (t & 3) << 2;     // 64 rows x 4 float4-cols
    float invA = inv[b * NN + m0 + lrow];
    float invB = inv[b * NN + n0 + lrow];
    const float* gA = feats + (size_t)(m0 + lrow) * DD + lc4;
    const float* gB = feats + (size_t)(n0 + lrow) * DD + lc4;
    int tx = t & 15, ty = t >> 4;
    float acc[4][4] = {};
    for (int k0 = 0; k0 < DD; k0 += KC) {
        float4 a = *(const float4*)(gA + k0);
        float4 bv = *(const float4*)(gB + k0);
        __syncthreads();
        // store transposed [k][m], scaled at load (matches reference normalize-then-dot)
        As[(lc4 + 0) * LDT + lrow] = a.x * invA;
        As[(lc4 + 1) * LDT + lrow] = a.y * invA;
        As[(lc4 + 2) * LDT + lrow] = a.z * invA;
        As[(lc4 + 3) * LDT + lrow] = a.w * invA;
        Bs[(lc4 + 0) * LDT + lrow] = bv.x * invB;
        Bs[(lc4 + 1) * LDT + lrow] = bv.y * invB;
        Bs[(lc4 + 2) * LDT + lrow] = bv.z * invB;
        Bs[(lc4 + 3) * LDT + lrow] = bv.w * invB;
        __syncthreads();
#pragma unroll
        for (int kk = 0; kk < KC; kk++) {
            float4 av = *(const float4*)&As[kk * LDT + (tx << 2)];
            float4 bw = *(const float4*)&Bs[kk * LDT + (ty << 2)];
            float aa[4] = {av.x, av.y, av.z, av.w};
            float bb[4] = {bw.x, bw.y, bw.z, bw.w};
#pragma unroll
            for (int i = 0; i < 4; i++)
#pragma unroll
                for (int j = 0; j < 4; j++) acc[i][j] += aa[i] * bb[j];
        }
    }
    // normal-orientation tile write (coalesced float4)
#pragma unroll
    for (int i = 0; i < 4; i++) {
        size_t m = m0 + (tx << 2) + i;
        float4 o = {acc[i][0], acc[i][1], acc[i][2], acc[i][3]};
        *(float4*)(sim + ((size_t)b * NN + m) * NN + n0 + (ty << 2)) = o;
    }
    if (ti != tj) {
        // mirror tile via LDS bounce; same float values -> bitwise symmetric
        __syncthreads();
#pragma unroll
        for (int i = 0; i < 4; i++) {
            float4 o = {acc[i][0], acc[i][1], acc[i][2], acc[i][3]};
            *(float4*)&tile[((tx << 2) + i) * TLD + (ty << 2)] = o;
        }
        __syncthreads();
#pragma unroll
        for (int r = 0; r < 4; r++) {
            int a = (tx << 2) + r;                 // local n index (output row)
            float4 o;
            o.x = tile[((ty << 2) + 0) * TLD + a];
            o.y = tile[((ty << 2) + 1) * TLD + a];
            o.z = tile[((ty << 2) + 2) * TLD + a];
            o.w = tile[((ty << 2) + 3) * TLD + a];
            *(float4*)(sim + ((size_t)b * NN + n0 + a) * NN + m0 + (ty << 2)) = o;
        }
    }
}

// ------- selection: 9 waves, zero barriers in loop, 2 LDS rendezvous/step ---
// Thread t owns candidate t; gain in fp64 register. Per step:
//   phase1: poll done==k-1 -> rebuild flat chlist from 9 ballot masks (each
//           wave writes its own full copy; same-value races benign; ascending
//           n -> deterministic fp64 order) -> ILP-16 delta update of g.
//   argmax: wave shuffle-reduce, post rv/ri, poll rtag==k, scan 9 slots.
//   tail:   load sim row mstar, update cmax/oldv, ballot -> chmask[w],
//           fence, post done=k.
// Safety: state-k writes occur only after rtag-poll(k) passed, i.e. after all
// waves finished phase1(k) reads of state k-1. rv/ri(k+1) writes occur after
// done-poll(k), i.e. after all waves' scan(k) reads. Monotone tags, no reuse.
__global__ __launch_bounds__(576) void select_kernel(const float* __restrict__ sim,
                                                     const float* __restrict__ cls,
                                                     float* __restrict__ out_idx,
                                                     int* __restrict__ gsorted) {
    int b = blockIdx.x;
    const float* S = sim + (size_t)b * NN * NN;
    int t = threadIdx.x, lane = t & 63, w = t >> 6;
    __shared__ float cmax[NN];
    __shared__ float oldv[NN];
    __shared__ int   chlist[NN];
    __shared__ unsigned long long chmask[9];
    __shared__ double rv[9];
    __shared__ int ri[9];
    __shared__ int rtag[9];
    __shared__ int done[9];
    __shared__ int wcnt[9];
    volatile int* vrtag = rtag;
    volatile int* vdone = done;

    float clsv = cls[b * NN + t];
    bool sel = false;
    cmax[t] = 0.f;
    if (lane == 0) { rtag[w] = -1; done[w] = -1; }

    // initial gains: column t (== row t by bitwise symmetry), ILP-16
    double g = 0.0;
    {
        const float* Sc = S + t;
        for (int n = 0; n < NN; n += 16) {
            float x[16];
#pragma unroll
            for (int q = 0; q < 16; q++) x[q] = Sc[(size_t)(n + q) * NN];
#pragma unroll
            for (int q = 0; q < 16; q++) g += (double)fmaxf(x[q], 0.f);
        }
    }
    __syncthreads();   // covers cmax + tag init (outside the hot loop)

    for (int k = 0; k < KK; k++) {
        // ---- phase 1: delta-update over step-(k-1) changed columns ----
        if (k > 0) {
            int km1 = k - 1;
            while (vdone[0] < km1 || vdone[1] < km1 || vdone[2] < km1 ||
                   vdone[3] < km1 || vdone[4] < km1 || vdone[5] < km1 ||
                   vdone[6] < km1 || vdone[7] < km1 || vdone[8] < km1) {}
            __threadfence_block();
            // rebuild flat ascending chlist from the 9 ballot masks.
            // Each wave writes the complete list itself (no cross-wave dep).
            int pos = 0;
#pragma unroll
            for (int q = 0; q < 9; q++) {
                unsigned long long m = chmask[q];
                if ((m >> lane) & 1ull)
                    chlist[pos + __popcll(m & ((1ull << lane) - 1ull))] = (q << 6) + lane;
                pos += __popcll(m);
            }
            int cc = pos;
            for (int j = 0; j < cc; j += 16) {
                int nq[16]; float x[16];
#pragma unroll
                for (int q = 0; q < 16; q++) {
                    int f = j + q; if (f > cc - 1) f = cc - 1;
                    nq[q] = chlist[f];
                }
#pragma unroll
                for (int q = 0; q < 16; q++) x[q] = S[(size_t)nq[q] * NN + t];
#pragma unroll
                for (int q = 0; q < 16; q++) {
                    float o = oldv[nq[q]], nw = cmax[nq[q]];
                    double d = (double)fmaxf(x[q] - nw, 0.f)
                             - (double)fmaxf(x[q] - o, 0.f);
                    g += (j + q < cc) ? d : 0.0;
                }
            }
        }
        // ---- wave argmax (smallest-index tie-break = jnp.argmax) ----
        double v = sel ? -1.0 : g * (double)clsv;   // gains >= 0 for unselected
        int idx = t;
        for (int off = 32; off; off >>= 1) {
            double ov = __shfl_xor(v, off);
            int oi = __shfl_xor(idx, off);
            if (ov > v || (ov == v && oi < idx)) { v = ov; idx = oi; }
        }
        if (lane == 0) { rv[w] = v; ri[w] = idx; __threadfence_block(); vrtag[w] = k; }
        while (vrtag[0] < k || vrtag[1] < k || vrtag[2] < k ||
               vrtag[3] < k || vrtag[4] < k || vrtag[5] < k ||
               vrtag[6] < k || vrtag[7] < k || vrtag[8] < k) {}
        __threadfence_block();
        double bv = rv[0]; int mstar = ri[0];
#pragma unroll
        for (int q = 1; q < 9; q++) {
            double qv = rv[q]; int qi = ri[q];
            if (qv > bv || (qv == bv && qi < mstar)) { bv = qv; mstar = qi; }
        }
        // ---- tail: cmax update + ballot mask ----
        float srow = S[(size_t)mstar * NN + t];
        float old = cmax[t];
        float nw = fmaxf(old, srow);
        bool ch = nw > old;
        unsigned long long m = __ballot(ch);
        oldv[t] = old;
        cmax[t] = nw;
        if (lane == 0) chmask[w] = m;
        if (t == mstar) { sel = true; out_idx[b * KK + k] = (float)(mstar + 1); }
        __threadfence_block();
        if (lane == 0) vdone[w] = k;
    }

    // ---- epilogue: sorted gather list (ascending index compaction) ----
    __syncthreads();
    unsigned long long mask = __ballot(sel);
    int rank = __popcll(mask & ((1ull << lane) - 1));
    if (lane == 0) wcnt[w] = __popcll(mask);
    __syncthreads();
    int pre = 0;
#pragma unroll
    for (int q = 0; q < 9; q++) if (q < w) pre += wcnt[q];
    if (sel) gsorted[b * KK + pre + rank] = t + 1;
}

// ---------------- gather: dominant_tokens[b,j,:] = hs[b, gsorted, :] --------
__global__ __launch_bounds__(256) void gather_kernel(const float* __restrict__ hs,
                                                     const int* __restrict__ gsorted,
                                                     float* __restrict__ out) {
    int blk = blockIdx.x;
    int b = blk >> 7, j = blk & 127;
    int row = gsorted[b * KK + j];
    const float4* src = (const float4*)(hs + ((size_t)b * HS_N + row) * DD);
    float4* dst = (float4*)(out + ((size_t)b * KK + j) * DD);
    dst[threadIdx.x] = src[threadIdx.x];
}

extern "C" void kernel_launch(void* const* d_in, const int* in_sizes, int n_in,
                              void* d_out, int out_size, void* d_ws, size_t ws_size,
                              hipStream_t stream) {
    const float* hs = (const float*)d_in[0];
    const float* cls = (const float*)d_in[1];
    // workspace layout: sim (42.5MB) | inv (73KB) | gsorted (16KB)
    float* sim = (float*)d_ws;
    float* inv = sim + (size_t)BB * NN * NN;
    int* gsorted = (int*)(inv + BB * NN);
    float* out_tokens = (float*)d_out;                       // [B,K,D] fp32
    float* out_idx = out_tokens + (size_t)BB * KK * DD;      // [B,K] indices as fp32

    norm_kernel<<<BB * NN, 256, 0, stream>>>(hs, inv);
    sim_kernel<<<dim3(45, 1, BB), 256, 0, stream>>>(hs, inv, sim);
    select_kernel<<<BB, 576, 0, stream>>>(sim, cls, out_idx, gsorted);
    gather_kernel<<<BB * KK, 256, 0, stream>>>(hs, gsorted, out_tokens);
}

// Round 6
// 1008.180 us; speedup vs baseline: 1.3091x; 1.0128x over previous
//
#include <hip/hip_runtime.h>

#define BB 32
#define NN 576
#define DD 1024
#define KK 128
#define HS_N 577

// ---------------- norm kernel: inv[b,n] = 1/||feats[b,n,:]|| ----------------
__global__ __launch_bounds__(256) void norm_kernel(const float* __restrict__ hs,
                                                   float* __restrict__ inv) {
    int row = blockIdx.x;              // b*NN + n
    int b = row / NN, n = row % NN;
    const float4* p = (const float4*)(hs + ((size_t)b * HS_N + n + 1) * DD);
    int t = threadIdx.x;
    float4 v = p[t];
    double s = (double)v.x * v.x + (double)v.y * v.y + (double)v.z * v.z + (double)v.w * v.w;
    for (int off = 32; off; off >>= 1) s += __shfl_xor(s, off);
    __shared__ double wsum[4];
    int lane = t & 63, w = t >> 6;
    if (lane == 0) wsum[w] = s;
    __syncthreads();
    if (t == 0) {
        double tot = wsum[0] + wsum[1] + wsum[2] + wsum[3];
        inv[row] = 1.0f / (float)sqrt(tot);
    }
}

// ---------------- sim GEMM (symmetric): only 45 upper-tri 64x64 tile pairs --
#define KC 16
#define LDT 68   // padded LDS stride
#define TLD 68   // transpose-bounce stride
__global__ __launch_bounds__(256) void sim_kernel(const float* __restrict__ hs,
                                                  const float* __restrict__ inv,
                                                  float* __restrict__ sim) {
    int b = blockIdx.z;
    int l = blockIdx.x;                // 0..44 -> (ti,tj), ti<=tj
    int ti = 0;
    while (l >= 9 - ti) { l -= 9 - ti; ti++; }
    int tj = ti + l;
    int m0 = ti * 64, n0 = tj * 64;
    const float* feats = hs + ((size_t)b * HS_N + 1) * DD;
    __shared__ float As[KC * LDT];
    __shared__ float Bs[KC * LDT];
    __shared__ float tile[64 * TLD];
    int t = threadIdx.x;
    int lrow = t >> 2, lc4 = (t & 3) << 2;     // 64 rows x 4 float4-cols
    float invA = inv[b * NN + m0 + lrow];
    float invB = inv[b * NN + n0 + lrow];
    const float* gA = feats + (size_t)(m0 + lrow) * DD + lc4;
    const float* gB = feats + (size_t)(n0 + lrow) * DD + lc4;
    int tx = t & 15, ty = t >> 4;
    float acc[4][4] = {};
    for (int k0 = 0; k0 < DD; k0 += KC) {
        float4 a = *(const float4*)(gA + k0);
        float4 bv = *(const float4*)(gB + k0);
        __syncthreads();
        // store transposed [k][m], scaled at load (matches reference normalize-then-dot)
        As[(lc4 + 0) * LDT + lrow] = a.x * invA;
        As[(lc4 + 1) * LDT + lrow] = a.y * invA;
        As[(lc4 + 2) * LDT + lrow] = a.z * invA;
        As[(lc4 + 3) * LDT + lrow] = a.w * invA;
        Bs[(lc4 + 0) * LDT + lrow] = bv.x * invB;
        Bs[(lc4 + 1) * LDT + lrow] = bv.y * invB;
        Bs[(lc4 + 2) * LDT + lrow] = bv.z * invB;
        Bs[(lc4 + 3) * LDT + lrow] = bv.w * invB;
        __syncthreads();
#pragma unroll
        for (int kk = 0; kk < KC; kk++) {
            float4 av = *(const float4*)&As[kk * LDT + (tx << 2)];
            float4 bw = *(const float4*)&Bs[kk * LDT + (ty << 2)];
            float aa[4] = {av.x, av.y, av.z, av.w};
            float bb[4] = {bw.x, bw.y, bw.z, bw.w};
#pragma unroll
            for (int i = 0; i < 4; i++)
#pragma unroll
                for (int j = 0; j < 4; j++) acc[i][j] += aa[i] * bb[j];
        }
    }
    // normal-orientation tile write (coalesced float4)
#pragma unroll
    for (int i = 0; i < 4; i++) {
        size_t m = m0 + (tx << 2) + i;
        float4 o = {acc[i][0], acc[i][1], acc[i][2], acc[i][3]};
        *(float4*)(sim + ((size_t)b * NN + m) * NN + n0 + (ty << 2)) = o;
    }
    if (ti != tj) {
        // mirror tile via LDS bounce; same float values -> bitwise symmetric
        __syncthreads();
#pragma unroll
        for (int i = 0; i < 4; i++) {
            float4 o = {acc[i][0], acc[i][1], acc[i][2], acc[i][3]};
            *(float4*)&tile[((tx << 2) + i) * TLD + (ty << 2)] = o;
        }
        __syncthreads();
#pragma unroll
        for (int r = 0; r < 4; r++) {
            int a = (tx << 2) + r;                 // local n index (output row)
            float4 o;
            o.x = tile[((ty << 2) + 0) * TLD + a];
            o.y = tile[((ty << 2) + 1) * TLD + a];
            o.z = tile[((ty << 2) + 2) * TLD + a];
            o.w = tile[((ty << 2) + 3) * TLD + a];
            *(float4*)(sim + ((size_t)b * NN + n0 + a) * NN + m0 + (ty << 2)) = o;
        }
    }
}

// ------- selection: 9 waves, 2 barriers/step, ILP-32 delta updates ----------
// Thread t owns candidate t; gain g and cmax[t] live in registers. Per step:
//   phase1: rebuild flat ascending chlist from 9 ballot masks (each wave
//           writes its own complete copy -> reads only its own writes, no
//           barrier; same-value cross-wave races benign) then ILP-32
//           delta-update of g (exact fp64 telescoping, fixed ascending order).
//   argmax: wave shuffle-reduce (fp64, smallest-index ties) -> post rv/ri
//           -> barrier A -> all threads scan 9 slots.
//   tail:   load sim row mstar (coalesced), update own cmax, ballot ->
//           chmask[w], pack (old,new) float2 -> barrier B.
// launch_bounds(576,3): VGPR cap ~170 so nq[32]/x[32] stay in registers
// (R3's VGPR=36 serialized the load stream -- the round-5 lesson).
__global__ __launch_bounds__(576, 3) void select_kernel(const float* __restrict__ sim,
                                                        const float* __restrict__ cls,
                                                        float* __restrict__ out_idx,
                                                        int* __restrict__ gsorted) {
    int b = blockIdx.x;
    const float* S = sim + (size_t)b * NN * NN;
    int t = threadIdx.x, lane = t & 63, w = t >> 6;
    __shared__ float2 ovnw[NN];            // (old cmax, new cmax) per column
    __shared__ int    chlist[NN];
    __shared__ unsigned long long chmask[9];
    __shared__ double rv[9];
    __shared__ int ri[9];
    __shared__ int wcnt[9];

    float clsv = cls[b * NN + t];
    bool sel = false;
    float mycmax = 0.f;                    // cmax[t] lives in owner's register

    // initial gains: column t (== row t by bitwise symmetry), ILP-32
    double g = 0.0;
    {
        const float* Sc = S + t;
        for (int n = 0; n < NN; n += 32) {
            float x[32];
#pragma unroll
            for (int q = 0; q < 32; q++) x[q] = Sc[(size_t)(n + q) * NN];
#pragma unroll
            for (int q = 0; q < 32; q++) g += (double)fmaxf(x[q], 0.f);
        }
    }

    for (int k = 0; k < KK; k++) {
        // ---- phase 1: delta-update over step-(k-1) changed columns ----
        if (k > 0) {
            int pos = 0;
#pragma unroll
            for (int q = 0; q < 9; q++) {
                unsigned long long m = chmask[q];
                if ((m >> lane) & 1ull)
                    chlist[pos + __popcll(m & ((1ull << lane) - 1ull))] = (q << 6) + lane;
                pos += __popcll(m);
            }
            int cc = pos;
            for (int j = 0; j < cc; j += 32) {
                int nq[32]; float x[32];
#pragma unroll
                for (int q = 0; q < 32; q++) {
                    int f = j + q; f = (f < cc) ? f : cc - 1;
                    nq[q] = chlist[f];
                }
#pragma unroll
                for (int q = 0; q < 32; q++) x[q] = S[(size_t)nq[q] * NN + t];
#pragma unroll
                for (int q = 0; q < 32; q++) {
                    float2 on = ovnw[nq[q]];
                    double d = (double)fmaxf(x[q] - on.y, 0.f)
                             - (double)fmaxf(x[q] - on.x, 0.f);
                    g += (j + q < cc) ? d : 0.0;
                }
            }
        }
        // ---- wave argmax (smallest-index tie-break = jnp.argmax) ----
        double v = sel ? -1.0 : g * (double)clsv;   // gains >= 0 for unselected
        int idx = t;
        for (int off = 32; off; off >>= 1) {
            double ov = __shfl_xor(v, off);
            int oi = __shfl_xor(idx, off);
            if (ov > v || (ov == v && oi < idx)) { v = ov; idx = oi; }
        }
        if (lane == 0) { rv[w] = v; ri[w] = idx; }
        __syncthreads();                           // A
        double bv = rv[0]; int mstar = ri[0];
#pragma unroll
        for (int q = 1; q < 9; q++) {
            double qv = rv[q]; int qi = ri[q];
            if (qv > bv || (qv == bv && qi < mstar)) { bv = qv; mstar = qi; }
        }
        // ---- tail: row load, cmax update, ballot mask ----
        float srow = S[(size_t)mstar * NN + t];
        float old = mycmax;
        float nw = fmaxf(old, srow);
        bool ch = nw > old;
        unsigned long long m = __ballot(ch);
        ovnw[t] = make_float2(old, nw);
        mycmax = nw;
        if (lane == 0) chmask[w] = m;
        if (t == mstar) { sel = true; out_idx[b * KK + k] = (float)(mstar + 1); }
        __syncthreads();                           // B
    }

    // ---- epilogue: sorted gather list (ascending index compaction) ----
    unsigned long long mask = __ballot(sel);
    int rank = __popcll(mask & ((1ull << lane) - 1));
    if (lane == 0) wcnt[w] = __popcll(mask);
    __syncthreads();
    int pre = 0;
#pragma unroll
    for (int q = 0; q < 9; q++) if (q < w) pre += wcnt[q];
    if (sel) gsorted[b * KK + pre + rank] = t + 1;
}

// ---------------- gather: dominant_tokens[b,j,:] = hs[b, gsorted, :] --------
__global__ __launch_bounds__(256) void gather_kernel(const float* __restrict__ hs,
                                                     const int* __restrict__ gsorted,
                                                     float* __restrict__ out) {
    int blk = blockIdx.x;
    int b = blk >> 7, j = blk & 127;
    int row = gsorted[b * KK + j];
    const float4* src = (const float4*)(hs + ((size_t)b * HS_N + row) * DD);
    float4* dst = (float4*)(out + ((size_t)b * KK + j) * DD);
    dst[threadIdx.x] = src[threadIdx.x];
}

extern "C" void kernel_launch(void* const* d_in, const int* in_sizes, int n_in,
                              void* d_out, int out_size, void* d_ws, size_t ws_size,
                              hipStream_t stream) {
    const float* hs = (const float*)d_in[0];
    const float* cls = (const float*)d_in[1];
    // workspace layout: sim (42.5MB) | inv (73KB) | gsorted (16KB)
    float* sim = (float*)d_ws;
    float* inv = sim + (size_t)BB * NN * NN;
    int* gsorted = (int*)(inv + BB * NN);
    float* out_tokens = (float*)d_out;                       // [B,K,D] fp32
    float* out_idx = out_tokens + (size_t)BB * KK * DD;      // [B,K] indices as fp32

    norm_kernel<<<BB * NN, 256, 0, stream>>>(hs, inv);
    sim_kernel<<<dim3(45, 1, BB), 256, 0, stream>>>(hs, inv, sim);
    select_kernel<<<BB, 576, 0, stream>>>(sim, cls, out_idx, gsorted);
    gather_kernel<<<BB * KK, 256, 0, stream>>>(hs, gsorted, out_tokens);
}

// Round 7
// 848.560 us; speedup vs baseline: 1.5554x; 1.1881x over previous
//
#include <hip/hip_runtime.h>

#define BB 32
#define NN 576
#define DD 1024
#define KK 128
#define HS_N 577

// ---------------- norm kernel: inv[b,n] = 1/||feats[b,n,:]|| ----------------
__global__ __launch_bounds__(256) void norm_kernel(const float* __restrict__ hs,
                                                   float* __restrict__ inv) {
    int row = blockIdx.x;              // b*NN + n
    int b = row / NN, n = row % NN;
    const float4* p = (const float4*)(hs + ((size_t)b * HS_N + n + 1) * DD);
    int t = threadIdx.x;
    float4 v = p[t];
    double s = (double)v.x * v.x + (double)v.y * v.y + (double)v.z * v.z + (double)v.w * v.w;
    for (int off = 32; off; off >>= 1) s += __shfl_xor(s, off);
    __shared__ double wsum[4];
    int lane = t & 63, w = t >> 6;
    if (lane == 0) wsum[w] = s;
    __syncthreads();
    if (t == 0) {
        double tot = wsum[0] + wsum[1] + wsum[2] + wsum[3];
        inv[row] = 1.0f / (float)sqrt(tot);
    }
}

// ---------------- sim GEMM (symmetric): only 45 upper-tri 64x64 tile pairs --
#define KC 16
#define LDT 68   // padded LDS stride
#define TLD 68   // transpose-bounce stride
__global__ __launch_bounds__(256) void sim_kernel(const float* __restrict__ hs,
                                                  const float* __restrict__ inv,
                                                  float* __restrict__ sim) {
    int b = blockIdx.z;
    int l = blockIdx.x;                // 0..44 -> (ti,tj), ti<=tj
    int ti = 0;
    while (l >= 9 - ti) { l -= 9 - ti; ti++; }
    int tj = ti + l;
    int m0 = ti * 64, n0 = tj * 64;
    const float* feats = hs + ((size_t)b * HS_N + 1) * DD;
    __shared__ float As[KC * LDT];
    __shared__ float Bs[KC * LDT];
    __shared__ float tile[64 * TLD];
    int t = threadIdx.x;
    int lrow = t >> 2, lc4 = (t & 3) << 2;     // 64 rows x 4 float4-cols
    float invA = inv[b * NN + m0 + lrow];
    float invB = inv[b * NN + n0 + lrow];
    const float* gA = feats + (size_t)(m0 + lrow) * DD + lc4;
    const float* gB = feats + (size_t)(n0 + lrow) * DD + lc4;
    int tx = t & 15, ty = t >> 4;
    float acc[4][4] = {};
    for (int k0 = 0; k0 < DD; k0 += KC) {
        float4 a = *(const float4*)(gA + k0);
        float4 bv = *(const float4*)(gB + k0);
        __syncthreads();
        // store transposed [k][m], scaled at load (matches reference normalize-then-dot)
        As[(lc4 + 0) * LDT + lrow] = a.x * invA;
        As[(lc4 + 1) * LDT + lrow] = a.y * invA;
        As[(lc4 + 2) * LDT + lrow] = a.z * invA;
        As[(lc4 + 3) * LDT + lrow] = a.w * invA;
        Bs[(lc4 + 0) * LDT + lrow] = bv.x * invB;
        Bs[(lc4 + 1) * LDT + lrow] = bv.y * invB;
        Bs[(lc4 + 2) * LDT + lrow] = bv.z * invB;
        Bs[(lc4 + 3) * LDT + lrow] = bv.w * invB;
        __syncthreads();
#pragma unroll
        for (int kk = 0; kk < KC; kk++) {
            float4 av = *(const float4*)&As[kk * LDT + (tx << 2)];
            float4 bw = *(const float4*)&Bs[kk * LDT + (ty << 2)];
            float aa[4] = {av.x, av.y, av.z, av.w};
            float bb[4] = {bw.x, bw.y, bw.z, bw.w};
#pragma unroll
            for (int i = 0; i < 4; i++)
#pragma unroll
                for (int j = 0; j < 4; j++) acc[i][j] += aa[i] * bb[j];
        }
    }
    // normal-orientation tile write (coalesced float4)
#pragma unroll
    for (int i = 0; i < 4; i++) {
        size_t m = m0 + (tx << 2) + i;
        float4 o = {acc[i][0], acc[i][1], acc[i][2], acc[i][3]};
        *(float4*)(sim + ((size_t)b * NN + m) * NN + n0 + (ty << 2)) = o;
    }
    if (ti != tj) {
        // mirror tile via LDS bounce; same float values -> bitwise symmetric
        __syncthreads();
#pragma unroll
        for (int i = 0; i < 4; i++) {
            float4 o = {acc[i][0], acc[i][1], acc[i][2], acc[i][3]};
            *(float4*)&tile[((tx << 2) + i) * TLD + (ty << 2)] = o;
        }
        __syncthreads();
#pragma unroll
        for (int r = 0; r < 4; r++) {
            int a = (tx << 2) + r;                 // local n index (output row)
            float4 o;
            o.x = tile[((ty << 2) + 0) * TLD + a];
            o.y = tile[((ty << 2) + 1) * TLD + a];
            o.z = tile[((ty << 2) + 2) * TLD + a];
            o.w = tile[((ty << 2) + 3) * TLD + a];
            *(float4*)(sim + ((size_t)b * NN + n0 + a) * NN + m0 + (ty << 2)) = o;
        }
    }
}

// -------- init gains on all CUs: g0[b,m] = sum_n max(sim[b,m,n],0) ----------
__global__ __launch_bounds__(256) void init_gain_kernel(const float* __restrict__ sim,
                                                        double* __restrict__ g0) {
    int b = blockIdx.y;
    int m = (blockIdx.x << 2) + (threadIdx.x >> 6);
    int lane = threadIdx.x & 63;
    const float* row = sim + ((size_t)b * NN + m) * NN;
    double s = 0.0;
#pragma unroll
    for (int j = 0; j < 9; j++) s += (double)fmaxf(row[(j << 6) + lane], 0.f);
    for (int off = 32; off; off >>= 1) s += __shfl_xor(s, off);
    if (lane == 0) g0[b * NN + m] = s;
}

// ------- selection: 3 waves x 3 candidates, 2 light barriers/step -----------
// Thread t owns candidates c_u = t + 192u (chunk 3u+w covers cols [64*(3u+w),
// +64) -- ascending). gains gg[u] (fp64) + cmax in registers. Per step:
//   phase1 (k>0): rebuild ascending chlist from 9 ballot masks (wave-uniform
//     broadcast reads; each wave writes full copy, same-value races benign),
//     then ILP-16x3 delta update (48 loads in flight; launch_bounds(192,1)
//     gives the 256-VGPR budget so the arrays stay register-resident --
//     rounds 4/5/6 showed register starvation serializes the load stream).
//   argmax: 3-way local (ascending c ties) -> wave shuffle -> rv/ri -> bar A
//     -> scan 3 slots.
//   tail: 3 coalesced row loads, cmax update, ballots -> chmask, selseq in
//     LDS (NO global ops in loop -> no vmcnt(0) store drain at barriers).
__global__ __launch_bounds__(192, 1) void select_kernel(const float* __restrict__ sim,
                                                        const double* __restrict__ g0,
                                                        const float* __restrict__ cls,
                                                        float* __restrict__ out_idx,
                                                        int* __restrict__ gsorted) {
    int b = blockIdx.x;
    const float* S = sim + (size_t)b * NN * NN;
    int t = threadIdx.x, lane = t & 63, w = t >> 6;   // w in 0..2
    __shared__ float2 ovnw[NN];            // (old cmax, new cmax) per column
    __shared__ int    chlist[NN];
    __shared__ unsigned long long chmask[9];
    __shared__ double rv[3];
    __shared__ int    ri[3];
    __shared__ float  selseq[KK];
    __shared__ int    wcnt9[9];

    double gg[3], cl[3];
    float mycmax[3] = {0.f, 0.f, 0.f};
    bool sel[3] = {false, false, false};
#pragma unroll
    for (int u = 0; u < 3; u++) {
        cl[u] = (double)cls[b * NN + t + 192 * u];
        gg[u] = g0[b * NN + t + 192 * u];
    }
    const int c0 = t, c1 = t + 192, c2 = t + 384;

    for (int k = 0; k < KK; k++) {
        // ---- phase 1: delta-update over step-(k-1) changed columns ----
        if (k > 0) {
            int pos = 0;
#pragma unroll
            for (int q = 0; q < 9; q++) {
                unsigned long long m = chmask[q];
                if ((m >> lane) & 1ull)
                    chlist[pos + __popcll(m & ((1ull << lane) - 1ull))] = (q << 6) + lane;
                pos += __popcll(m);
            }
            int cc = pos;
            for (int j = 0; j < cc; j += 16) {
                int nq[16]; float x0[16], x1[16], x2[16]; float2 on[16];
#pragma unroll
                for (int q = 0; q < 16; q++) {
                    int f = j + q; f = (f < cc) ? f : cc - 1;
                    nq[q] = chlist[f];                    // wave-uniform
                }
#pragma unroll
                for (int q = 0; q < 16; q++) {
                    const float* rp = S + (size_t)nq[q] * NN + t;
                    x0[q] = rp[0]; x1[q] = rp[192]; x2[q] = rp[384];
                }
#pragma unroll
                for (int q = 0; q < 16; q++) on[q] = ovnw[nq[q]];  // broadcast
#pragma unroll
                for (int q = 0; q < 16; q++) {
                    bool val = (j + q) < cc;
                    float o = on[q].x, nw = on[q].y;
                    double d0 = (double)fmaxf(x0[q] - nw, 0.f) - (double)fmaxf(x0[q] - o, 0.f);
                    double d1 = (double)fmaxf(x1[q] - nw, 0.f) - (double)fmaxf(x1[q] - o, 0.f);
                    double d2 = (double)fmaxf(x2[q] - nw, 0.f) - (double)fmaxf(x2[q] - o, 0.f);
                    gg[0] += val ? d0 : 0.0;
                    gg[1] += val ? d1 : 0.0;
                    gg[2] += val ? d2 : 0.0;
                }
            }
        }
        // ---- argmax: local 3-way (strict > keeps smaller c on ties) ----
        double v = sel[0] ? -1.0 : gg[0] * cl[0];
        int idx = c0;
        {
            double v1 = sel[1] ? -1.0 : gg[1] * cl[1];
            if (v1 > v) { v = v1; idx = c1; }
            double v2 = sel[2] ? -1.0 : gg[2] * cl[2];
            if (v2 > v) { v = v2; idx = c2; }
        }
        for (int off = 32; off; off >>= 1) {
            double ov = __shfl_xor(v, off);
            int oi = __shfl_xor(idx, off);
            if (ov > v || (ov == v && oi < idx)) { v = ov; idx = oi; }
        }
        if (lane == 0) { rv[w] = v; ri[w] = idx; }
        __syncthreads();                           // A
        double bv = rv[0]; int mstar = ri[0];
        { double qv = rv[1]; int qi = ri[1]; if (qv > bv || (qv == bv && qi < mstar)) { bv = qv; mstar = qi; } }
        { double qv = rv[2]; int qi = ri[2]; if (qv > bv || (qv == bv && qi < mstar)) { bv = qv; mstar = qi; } }
        // ---- tail: 3 coalesced row loads, cmax update, ballots ----
        const float* rowm = S + (size_t)mstar * NN + t;
        float s0 = rowm[0], s1 = rowm[192], s2 = rowm[384];
        float o0 = mycmax[0], n0 = fmaxf(o0, s0); bool h0 = n0 > o0;
        float o1 = mycmax[1], n1 = fmaxf(o1, s1); bool h1 = n1 > o1;
        float o2 = mycmax[2], n2 = fmaxf(o2, s2); bool h2 = n2 > o2;
        unsigned long long m0 = __ballot(h0);
        unsigned long long m1 = __ballot(h1);
        unsigned long long m2 = __ballot(h2);
        ovnw[c0] = make_float2(o0, n0); mycmax[0] = n0;
        ovnw[c1] = make_float2(o1, n1); mycmax[1] = n1;
        ovnw[c2] = make_float2(o2, n2); mycmax[2] = n2;
        if (lane == 0) { chmask[w] = m0; chmask[3 + w] = m1; chmask[6 + w] = m2; }
        if (c0 == mstar) { sel[0] = true; selseq[k] = (float)(mstar + 1); }
        if (c1 == mstar) { sel[1] = true; selseq[k] = (float)(mstar + 1); }
        if (c2 == mstar) { sel[2] = true; selseq[k] = (float)(mstar + 1); }
        __syncthreads();                           // B
    }

    // ---- epilogue: write selection order + sorted gather list ----
    if (t < KK) out_idx[b * KK + t] = selseq[t];
    unsigned long long mk0 = __ballot(sel[0]);
    unsigned long long mk1 = __ballot(sel[1]);
    unsigned long long mk2 = __ballot(sel[2]);
    if (lane == 0) {
        wcnt9[w] = __popcll(mk0);
        wcnt9[3 + w] = __popcll(mk1);
        wcnt9[6 + w] = __popcll(mk2);
    }
    __syncthreads();
    int r0 = __popcll(mk0 & ((1ull << lane) - 1));
    int r1 = __popcll(mk1 & ((1ull << lane) - 1));
    int r2 = __popcll(mk2 & ((1ull << lane) - 1));
    int pre0 = 0, pre1 = 0, pre2 = 0;
#pragma unroll
    for (int q = 0; q < 9; q++) {
        int c = wcnt9[q];
        if (q < 0 + w) pre0 += c;
        if (q < 3 + w) pre1 += c;
        if (q < 6 + w) pre2 += c;
    }
    if (sel[0]) gsorted[b * KK + pre0 + r0] = c0 + 1;
    if (sel[1]) gsorted[b * KK + pre1 + r1] = c1 + 1;
    if (sel[2]) gsorted[b * KK + pre2 + r2] = c2 + 1;
}

// ---------------- gather: dominant_tokens[b,j,:] = hs[b, gsorted, :] --------
__global__ __launch_bounds__(256) void gather_kernel(const float* __restrict__ hs,
                                                     const int* __restrict__ gsorted,
                                                     float* __restrict__ out) {
    int blk = blockIdx.x;
    int b = blk >> 7, j = blk & 127;
    int row = gsorted[b * KK + j];
    const float4* src = (const float4*)(hs + ((size_t)b * HS_N + row) * DD);
    float4* dst = (float4*)(out + ((size_t)b * KK + j) * DD);
    dst[threadIdx.x] = src[threadIdx.x];
}

extern "C" void kernel_launch(void* const* d_in, const int* in_sizes, int n_in,
                              void* d_out, int out_size, void* d_ws, size_t ws_size,
                              hipStream_t stream) {
    const float* hs = (const float*)d_in[0];
    const float* cls = (const float*)d_in[1];
    // workspace layout: sim (42.5MB) | X: inv (norm->sim) / g0 (init->select,
    // lifetimes disjoint, g0 overlays inv) | gsorted (16KB)
    float* sim = (float*)d_ws;
    char* xregion = (char*)(sim + (size_t)BB * NN * NN);
    float* inv = (float*)xregion;                  // BB*NN floats
    double* g0 = (double*)xregion;                 // BB*NN doubles (overlay)
    int* gsorted = (int*)(xregion + (size_t)BB * NN * sizeof(double));
    float* out_tokens = (float*)d_out;                       // [B,K,D] fp32
    float* out_idx = out_tokens + (size_t)BB * KK * DD;      // [B,K] indices as fp32

    norm_kernel<<<BB * NN, 256, 0, stream>>>(hs, inv);
    sim_kernel<<<dim3(45, 1, BB), 256, 0, stream>>>(hs, inv, sim);
    init_gain_kernel<<<dim3(NN / 4, BB), 256, 0, stream>>>(sim, g0);
    select_kernel<<<BB, 192, 0, stream>>>(sim, g0, cls, out_idx, gsorted);
    gather_kernel<<<BB * KK, 256, 0, stream>>>(hs, gsorted, out_tokens);
}